// Round 3
// baseline (341.926 us; speedup 1.0000x reference)
//
#include <hip/hip_runtime.h>

#define NC 1000
#define FD 256
#define KPI 100    // labels per image (K)
#define CAP 512    // index-list capacity (counts ~ Binom(200k,1e-3): 200 +/- 14; 512 = 22 sigma)

// ---- pass 1: per-class row-INDEX lists (4B scatter into L2-resident 2MB buffer)
// + presence bitmask M from labels_per_image ----
__global__ __launch_bounds__(256) void k_index(
    const int* __restrict__ labels, int n,
    const int* __restrict__ lpi, int bk,
    int* __restrict__ cursor, unsigned long long* __restrict__ M,
    int* __restrict__ idxbuf) {   // [NC*CAP] ints
    int gid = blockIdx.x * 256 + threadIdx.x;
    if (gid < bk) atomicOr(&M[lpi[gid]], 1ull << (gid / KPI));
    if (gid < n) {
        int lab = labels[gid];
        int pos = atomicAdd(&cursor[lab], 1);
        if (pos < CAP) idxbuf[lab * CAP + pos] = gid;
    }
}

// ---- pass 2: one block (512 thr = 8 waves) per class.
// Gather the class's rows straight from the fp32 feature matrix (contiguous
// aligned 1KB per row -> fully coalesced), normalize in-register via 64-lane
// shuffle reduce, accumulate fp32 per-wave partials; EMA + cooc epilogue. ----
__global__ __launch_bounds__(512) void k_class(
    const float* __restrict__ feat, int n, const int* __restrict__ idxbuf,
    const int* __restrict__ cursor,
    const float* __restrict__ protos, const int* __restrict__ init_mask,
    const int* __restrict__ step,
    const unsigned long long* __restrict__ M,
    const float* __restrict__ cooc_in,
    float* __restrict__ out_protos, float* __restrict__ out_init,
    float* __restrict__ out_cooc) {
    int c = blockIdx.x;
    int tid = threadIdx.x;
    int lane = tid & 63;
    int w = tid >> 6;            // wave 0..7
    int cnt = cursor[c];
    if (cnt < 0) cnt = 0;        // defensive (poisoned-ws paranoia)
    int cntd = cnt > CAP ? CAP : cnt;

    // stage this class's row indices in LDS, clamped into [0, n)
    __shared__ int sidx[CAP];
    for (int i = tid; i < cntd; i += 512) {
        int v = idxbuf[c * CAP + i];
        sidx[i] = (v < 0) ? 0 : (v >= n ? n - 1 : v);
    }
    __syncthreads();

    const float4* f4 = (const float4*)feat;   // lane owns dims [4*lane, 4*lane+4)
    float4 acc = make_float4(0.f, 0.f, 0.f, 0.f);

    // wave w sums rows w, w+8, ... with two gathers in flight
    for (int r = w; r < cntd; r += 16) {
        int r2 = r + 8;
        bool ok2 = r2 < cntd;
        int i0 = sidx[r];
        int i1 = sidx[ok2 ? r2 : r];
        float4 a = f4[(size_t)i0 * 64 + lane];
        float4 b = f4[(size_t)i1 * 64 + lane];
        float s0 = a.x * a.x + a.y * a.y + a.z * a.z + a.w * a.w;
        float s1 = b.x * b.x + b.y * b.y + b.z * b.z + b.w * b.w;
        #pragma unroll
        for (int o = 32; o; o >>= 1) {
            s0 += __shfl_xor(s0, o);
            s1 += __shfl_xor(s1, o);
        }
        float sc0 = 1.0f / fmaxf(sqrtf(s0), 1e-12f);
        float sc1 = 1.0f / fmaxf(sqrtf(s1), 1e-12f);
        acc.x += a.x * sc0; acc.y += a.y * sc0;
        acc.z += a.z * sc0; acc.w += a.w * sc0;
        if (ok2) {
            acc.x += b.x * sc1; acc.y += b.y * sc1;
            acc.z += b.z * sc1; acc.w += b.w * sc1;
        }
    }

    // combine 8 wave-partials via LDS
    __shared__ float4 sh4[512];
    sh4[w * 64 + lane] = acc;
    __syncthreads();

    if (tid < 64) {
        float4 s = make_float4(0.f, 0.f, 0.f, 0.f);
        #pragma unroll
        for (int q = 0; q < 8; q++) {
            float4 t = sh4[q * 64 + tid];
            s.x += t.x; s.y += t.y; s.z += t.z; s.w += t.w;
        }
        float inv = 1.0f / fmaxf((float)cnt, 1.0f);
        bool present = cnt > 0;
        bool inited = init_mask[c] > 0;
        float prog = fminf(1.0f, (float)step[0] / 2000.0f);   // WARMUP_STEPS*10
        float m = 0.99f + (0.999f - 0.99f) * prog;

        const float4* p4 = (const float4*)(protos + (size_t)c * FD);
        float4 p = p4[tid];
        float4 o;
        #define EMA1(mc, pc) (present ? (inited ? (m * (pc) + (1.0f - m) * ((mc) * inv)) \
                                                : ((mc) * inv)) : (pc))
        o.x = EMA1(s.x, p.x); o.y = EMA1(s.y, p.y);
        o.z = EMA1(s.z, p.z); o.w = EMA1(s.w, p.w);
        #undef EMA1
        ((float4*)(out_protos + (size_t)c * FD))[tid] = o;
        if (tid == 0) out_init[c] = (inited || present) ? 1.0f : 0.0f;
    }

    // cooc row c: 512 threads x 2 iters cover 1000 columns
    unsigned long long mi = M[c];
    for (int j = tid; j < NC; j += 512) {
        float add = (c == j) ? 0.0f : (float)__popcll(mi & M[j]);
        out_cooc[c * NC + j] = cooc_in[c * NC + j] + add;
    }
}

extern "C" void kernel_launch(void* const* d_in, const int* in_sizes, int n_in,
                              void* d_out, int out_size, void* d_ws, size_t ws_size,
                              hipStream_t stream) {
    const float* feat      = (const float*)d_in[0];
    const int*   labels    = (const int*)d_in[1];
    const int*   lpi       = (const int*)d_in[2];
    const float* protos    = (const float*)d_in[3];
    const int*   init_mask = (const int*)d_in[4];
    const float* cooc      = (const float*)d_in[5];
    const int*   step      = (const int*)d_in[6];

    int n  = in_sizes[1];   // 200000
    int bk = in_sizes[2];   // 6400

    float* out_protos = (float*)d_out;
    float* out_init   = out_protos + (size_t)NC * FD;
    float* out_cooc   = out_init + NC;

    // ws layout (bytes): [cursor 4096][M 8192][idxbuf NC*CAP*4 = 2 MB]
    char* ws = (char*)d_ws;
    int* cursor           = (int*)(ws);
    unsigned long long* M = (unsigned long long*)(ws + 4096);
    int* idxbuf           = (int*)(ws + 16384);

    hipMemsetAsync(d_ws, 0, 12288, stream);   // zero cursor + M

    int blocks = (n + 255) / 256;   // covers bk=6400 too
    k_index<<<blocks, 256, 0, stream>>>(labels, n, lpi, bk, cursor, M, idxbuf);
    k_class<<<NC, 512, 0, stream>>>(feat, n, idxbuf, cursor, protos, init_mask, step,
                                    M, cooc, out_protos, out_init, out_cooc);
}